// Round 3
// baseline (7679.810 us; speedup 1.0000x reference)
//
#include <hip/hip_runtime.h>
#include <stdint.h>

// ---------------- threefry2x32 (bit-exact vs JAX) ----------------
__device__ __forceinline__ uint32_t rotl32(uint32_t v, int r) {
    return (v << r) | (v >> (32 - r));
}

__device__ __forceinline__ void threefry2x32(uint32_t k0, uint32_t k1,
                                             uint32_t x0, uint32_t x1,
                                             uint32_t& o0, uint32_t& o1) {
    const uint32_t k2 = k0 ^ k1 ^ 0x1BD11BDAu;
    x0 += k0; x1 += k1;
#define TF_RND(r) { x0 += x1; x1 = rotl32(x1, r); x1 ^= x0; }
    TF_RND(13) TF_RND(15) TF_RND(26) TF_RND(6)
    x0 += k1; x1 += k2 + 1u;
    TF_RND(17) TF_RND(29) TF_RND(16) TF_RND(24)
    x0 += k2; x1 += k0 + 2u;
    TF_RND(13) TF_RND(15) TF_RND(26) TF_RND(6)
    x0 += k0; x1 += k1 + 3u;
    TF_RND(17) TF_RND(29) TF_RND(16) TF_RND(24)
    x0 += k1; x1 += k2 + 4u;
    TF_RND(13) TF_RND(15) TF_RND(26) TF_RND(6)
    x0 += k2; x1 += k0 + 5u;
#undef TF_RND
    o0 = x0; o1 = x1;
}

// ---------------- shared GEMM machinery ----------------
// Plane format for a matrix [R][K]: 64x64 tiles, tile-major [R/64][K/64],
// each tile = [hi: 4096 bf16][lo: 4096 bf16], element e swizzled:
//   e = ((r&63)*64 + (k&63)) ^ ((r&7)<<3)
// 3-product split: a*b ~= ah*bh + al*bh + ah*bl (rel err ~2^-18).

typedef __attribute__((ext_vector_type(8))) __bf16 bf16x8;
typedef __attribute__((ext_vector_type(4))) __bf16 bf16x4;
typedef __attribute__((ext_vector_type(4))) float f32x4;

__device__ __forceinline__ int swz_e(int r, int c) {
    return ((r & 63) * 64 + (c & 63)) ^ ((r & 7) << 3);
}

__device__ __forceinline__ void async16(const void* g, void* l) {
    __builtin_amdgcn_global_load_lds(
        (const __attribute__((address_space(1))) uint32_t*)g,
        (__attribute__((address_space(3))) uint32_t*)l,
        16, 0, 0);
}

// stage one 16KB plane tile (hi+lo) global -> LDS, async, linear
__device__ __forceinline__ void stageB(const __bf16* src, __bf16* dst, int tid) {
    const int wid = tid >> 6, lane = tid & 63;
    const char* g = (const char*)src + wid * 4096 + lane * 16;
    char* l = (char*)dst + wid * 4096 + lane * 16;
#pragma unroll
    for (int c = 0; c < 4; ++c)
        async16(g + c * 1024, l + c * 1024);
}

// ---------------- old-style 64x64 core (A fp32 cvt-in-kernel) ----------------
__device__ __forceinline__ void loadA(const float* A, long long lda,
                                      int m0, int k0, int tid, float4* ar) {
#pragma unroll
    for (int i = 0; i < 4; ++i) {
        const int flat = i * 256 + tid;
        const int row = flat >> 4, k4 = (flat & 15) << 2;
        ar[i] = *(const float4*)(A + (long long)(m0 + row) * lda + (k0 + k4));
    }
}

__device__ __forceinline__ void cvtWriteA(const float4* ar, __bf16* Hs, int tid) {
#pragma unroll
    for (int i = 0; i < 4; ++i) {
        const int flat = i * 256 + tid;
        const int row = flat >> 4, k4 = (flat & 15) << 2;
        const float4 v = ar[i];
        const __bf16 h0 = (__bf16)v.x, h1 = (__bf16)v.y, h2 = (__bf16)v.z, h3 = (__bf16)v.w;
        const __bf16 l0 = (__bf16)(v.x - (float)h0);
        const __bf16 l1 = (__bf16)(v.y - (float)h1);
        const __bf16 l2 = (__bf16)(v.z - (float)h2);
        const __bf16 l3 = (__bf16)(v.w - (float)h3);
        const int e = swz_e(row, k4);
        *(bf16x4*)&Hs[e] = (bf16x4){h0, h1, h2, h3};
        *(bf16x4*)&Hs[4096 + e] = (bf16x4){l0, l1, l2, l3};
    }
}

// computes 64x64 acc: C_tile = A[m0:,kbase:kbase+ksize] @ B[n0B:,:]^T
__device__ __forceinline__ void gemm64_core(
    __bf16* sA, __bf16* sB,
    const float* __restrict__ A, long long lda,
    const __bf16* __restrict__ Bp, int bKt,
    int m0, int n0B, int kbase, int ksize,
    f32x4 acc[2][2])
{
    const int tid  = threadIdx.x;
    const int lane = tid & 63;
    const int wid  = tid >> 6;
    const int wr   = (wid >> 1) << 5;
    const int wc   = (wid & 1) << 5;
    const int fr   = lane & 15;
    const int kg   = lane >> 4;
    const int nt   = ksize >> 6;
    const long long btile0 = (long long)(n0B >> 6) * bKt + (kbase >> 6);

    acc[0][0] = (f32x4){0,0,0,0}; acc[0][1] = (f32x4){0,0,0,0};
    acc[1][0] = (f32x4){0,0,0,0}; acc[1][1] = (f32x4){0,0,0,0};
    float4 ar[4];

    stageB(Bp + btile0 * 8192, sB, tid);
    loadA(A, lda, m0, kbase, tid, ar);
    cvtWriteA(ar, sA, tid);
    __syncthreads();

    for (int t = 0; t < nt; ++t) {
        const int cur = t & 1, nxt = cur ^ 1;
        __bf16* sAc = sA + cur * 8192;
        __bf16* sBc = sB + cur * 8192;
        if (t + 1 < nt) {
            stageB(Bp + (btile0 + t + 1) * 8192, sB + nxt * 8192, tid);
            loadA(A, lda, m0, kbase + ((t + 1) << 6), tid, ar);
        }
#pragma unroll
        for (int kc = 0; kc < 2; ++kc) {
            const int kb = kc * 32 + kg * 8;
            bf16x8 ah[2], al[2], bh[2], bl[2];
#pragma unroll
            for (int i = 0; i < 2; ++i) {
                const int r  = wr + i * 16 + fr;
                const int ea = swz_e(r, kb);
                ah[i] = *(const bf16x8*)&sAc[ea];
                al[i] = *(const bf16x8*)&sAc[4096 + ea];
                const int cc = wc + i * 16 + fr;
                const int eb = swz_e(cc, kb);
                bh[i] = *(const bf16x8*)&sBc[eb];
                bl[i] = *(const bf16x8*)&sBc[4096 + eb];
            }
#pragma unroll
            for (int i = 0; i < 2; ++i)
#pragma unroll
                for (int j = 0; j < 2; ++j)
                    acc[i][j] = __builtin_amdgcn_mfma_f32_16x16x32_bf16(ah[i], bh[j], acc[i][j], 0, 0, 0);
#pragma unroll
            for (int i = 0; i < 2; ++i)
#pragma unroll
                for (int j = 0; j < 2; ++j)
                    acc[i][j] = __builtin_amdgcn_mfma_f32_16x16x32_bf16(al[i], bh[j], acc[i][j], 0, 0, 0);
#pragma unroll
            for (int i = 0; i < 2; ++i)
#pragma unroll
                for (int j = 0; j < 2; ++j)
                    acc[i][j] = __builtin_amdgcn_mfma_f32_16x16x32_bf16(ah[i], bl[j], acc[i][j], 0, 0, 0);
        }
        if (t + 1 < nt)
            cvtWriteA(ar, sA + nxt * 8192, tid);
        __syncthreads();
    }
}

// ---------------- plane GEMM: TM=128 (full M), TN=64 ----------------
// A from planes (per-lane global->reg), B from planes via global_load_lds.
// 4 waves, wave w: rows w*32..w*32+31 (i=0..1), cols 0..63 (j=0..3).
__device__ __forceinline__ void plane_gemm(
    __bf16* sB,                                  // [2][8192]
    const __bf16* __restrict__ Ap, int aKt,
    const __bf16* __restrict__ Bp, int bKt,
    float* __restrict__ C, int ldc,
    int n0, int kbase, int ksize)
{
    const int tid  = threadIdx.x;
    const int lane = tid & 63;
    const int wid  = tid >> 6;
    const int wr   = wid << 5;
    const int fr   = lane & 15;
    const int kg   = lane >> 4;
    const int nt   = ksize >> 6;
    const int kt0  = kbase >> 6;
    const long long btile0 = (long long)(n0 >> 6) * bKt + kt0;

    f32x4 acc[2][4] = {};

    stageB(Bp + btile0 * 8192, sB, tid);
    __syncthreads();

    for (int t = 0; t < nt; ++t) {
        const int cur = t & 1;
        __bf16* sBc = sB + cur * 8192;
        if (t + 1 < nt)
            stageB(Bp + (btile0 + t + 1) * 8192, sB + (cur ^ 1) * 8192, tid);

        // A fragments for this k-tile, per-lane from global planes
        bf16x8 ah[2][2], al[2][2];               // [kc][i]
        const long long kt = (long long)(kt0 + t);
#pragma unroll
        for (int kc = 0; kc < 2; ++kc)
#pragma unroll
            for (int i = 0; i < 2; ++i) {
                const int r  = wr + i * 16 + fr;
                const int kb = kc * 32 + kg * 8;
                const long long ab = ((long long)(r >> 6) * aKt + kt) * 8192;
                const int ea = swz_e(r, kb);
                ah[kc][i] = *(const bf16x8*)&Ap[ab + ea];
                al[kc][i] = *(const bf16x8*)&Ap[ab + 4096 + ea];
            }
#pragma unroll
        for (int kc = 0; kc < 2; ++kc) {
            const int kb = kc * 32 + kg * 8;
            bf16x8 bh[4], bl[4];
#pragma unroll
            for (int j = 0; j < 4; ++j) {
                const int cc = j * 16 + fr;
                const int eb = swz_e(cc, kb);
                bh[j] = *(const bf16x8*)&sBc[eb];
                bl[j] = *(const bf16x8*)&sBc[4096 + eb];
            }
#pragma unroll
            for (int i = 0; i < 2; ++i)
#pragma unroll
                for (int j = 0; j < 4; ++j)
                    acc[i][j] = __builtin_amdgcn_mfma_f32_16x16x32_bf16(ah[kc][i], bh[j], acc[i][j], 0, 0, 0);
#pragma unroll
            for (int i = 0; i < 2; ++i)
#pragma unroll
                for (int j = 0; j < 4; ++j)
                    acc[i][j] = __builtin_amdgcn_mfma_f32_16x16x32_bf16(al[kc][i], bh[j], acc[i][j], 0, 0, 0);
#pragma unroll
            for (int i = 0; i < 2; ++i)
#pragma unroll
                for (int j = 0; j < 4; ++j)
                    acc[i][j] = __builtin_amdgcn_mfma_f32_16x16x32_bf16(ah[kc][i], bl[j], acc[i][j], 0, 0, 0);
        }
        __syncthreads();
    }

    // C/D layout: col = lane&15, row = (lane>>4)*4 + reg
#pragma unroll
    for (int i = 0; i < 2; ++i)
#pragma unroll
        for (int j = 0; j < 4; ++j)
#pragma unroll
            for (int v = 0; v < 4; ++v) {
                const int row = wr + i * 16 + kg * 4 + v;
                const int col = n0 + j * 16 + fr;
                C[(long long)row * ldc + col] = acc[i][j][v];
            }
}

// ---------------- per-step kernels ----------------

// K1: blocks 0..95: gh (plane GEMM, A=hp); blocks 96..223: embed (old core, atomic)
__global__ __launch_bounds__(256) void k_embed_gh(
    const float* __restrict__ out, const __bf16* __restrict__ pEt,
    float* __restrict__ x,
    const __bf16* __restrict__ hp, const __bf16* __restrict__ pHH,
    float* __restrict__ gh0, float* __restrict__ gh1, int t)
{
    __shared__ __align__(16) char smem[65536];
    const int bid = blockIdx.x;
    if (bid < 96) {
        __bf16* sB = (__bf16*)smem;
        const int n = bid >> 1, z = bid & 1;
        plane_gemm(sB, hp, 16, pHH, 16, z ? gh1 : gh0, 3072, n * 64, z * 512, 512);
    } else {
        if (t == 0) return;
        const int r = bid - 96;
        const int m0 = ((r >> 2) & 1) * 64;
        const int n0 = (r & 3) * 64;
        const int kbase = (r >> 3) * 512;
        const float* Y = out + (size_t)(t - 1) * 8192;
        __bf16* sA = (__bf16*)smem;
        __bf16* sB = (__bf16*)(smem + 32768);
        f32x4 acc[2][2];
        gemm64_core(sA, sB, Y, 128LL * 8192LL, pEt, 128, m0, n0, kbase, 512, acc);
        const int lane = threadIdx.x & 63, wid = threadIdx.x >> 6;
        const int wr = (wid >> 1) << 5, wc = (wid & 1) << 5;
        const int fr = lane & 15, kg = lane >> 4;
#pragma unroll
        for (int i = 0; i < 2; ++i)
#pragma unroll
            for (int j = 0; j < 2; ++j)
#pragma unroll
                for (int v = 0; v < 4; ++v) {
                    const int row = m0 + wr + i * 16 + kg * 4 + v;
                    const int col = n0 + wc + j * 16 + fr;
                    atomicAdd(&x[(long long)row * 256 + col], acc[i][j][v]);
                }
    }
}

// K2: gi (3 tiles, K=256) + gate nonlinearity + h/hp write.  grid 32 blocks.
__global__ __launch_bounds__(256) void k_gigates(
    const float* __restrict__ x, const __bf16* __restrict__ pIH,
    const float* __restrict__ b_ih, const float* __restrict__ b_hh,
    const float* __restrict__ gh0, const float* __restrict__ gh1,
    float* __restrict__ h, __bf16* __restrict__ hp)
{
    __shared__ __align__(16) __bf16 sA[2 * 8192];
    __shared__ __align__(16) __bf16 sB[2 * 8192];
    const int m0 = (blockIdx.x >> 4) * 64;
    const int n0 = (blockIdx.x & 15) * 64;
    f32x4 aR[2][2], aZ[2][2], aN[2][2];
    gemm64_core(sA, sB, x, 256, pIH, 4, m0, n0,        0, 256, aR);
    gemm64_core(sA, sB, x, 256, pIH, 4, m0, n0 + 1024, 0, 256, aZ);
    gemm64_core(sA, sB, x, 256, pIH, 4, m0, n0 + 2048, 0, 256, aN);

    const int lane = threadIdx.x & 63, wid = threadIdx.x >> 6;
    const int wr = (wid >> 1) << 5, wc = (wid & 1) << 5;
    const int fr = lane & 15, kg = lane >> 4;
#pragma unroll
    for (int i = 0; i < 2; ++i)
#pragma unroll
        for (int j = 0; j < 2; ++j)
#pragma unroll
            for (int v = 0; v < 4; ++v) {
                const int b   = m0 + wr + i * 16 + kg * 4 + v;
                const int col = n0 + wc + j * 16 + fr;   // 0..1023
                const float gir = aR[i][j][v] + b_ih[col];
                const float giz = aZ[i][j][v] + b_ih[col + 1024];
                const float gin = aN[i][j][v] + b_ih[col + 2048];
                const long long g = (long long)b * 3072 + col;
                const float ghr = gh0[g]        + gh1[g]        + b_hh[col];
                const float ghz = gh0[g + 1024] + gh1[g + 1024] + b_hh[col + 1024];
                const float ghn = gh0[g + 2048] + gh1[g + 2048] + b_hh[col + 2048];
                const float rr = 1.f / (1.f + expf(-(gir + ghr)));
                const float zz = 1.f / (1.f + expf(-(giz + ghz)));
                const float nn = tanhf(gin + rr * ghn);
                const float hv = (1.f - zz) * nn + zz * h[(long long)b * 1024 + col];
                h[(long long)b * 1024 + col] = hv;
                const __bf16 hh = (__bf16)hv;
                const __bf16 hl = (__bf16)(hv - (float)hh);
                const long long tb = ((long long)(b >> 6) * 16 + (col >> 6)) * 8192;
                const int e = swz_e(b, col);
                hp[tb + e] = hh;
                hp[tb + 4096 + e] = hl;
            }
}

// K3: logits split-K=2 via plane GEMM.  grid (128, 2).
__global__ __launch_bounds__(256) void k_logits(
    const __bf16* __restrict__ hp, const __bf16* __restrict__ pWo,
    float* __restrict__ lg0, float* __restrict__ lg1)
{
    __shared__ __align__(16) __bf16 sB[2 * 8192];
    const int n = blockIdx.x, z = blockIdx.y;
    plane_gemm(sB, hp, 16, pWo, 16, z ? lg1 : lg0, 8192, n * 64, z * 512, 512);
}

// ---------------- one-time kernels ----------------
__global__ __launch_bounds__(256) void k_h0(
    const float* __restrict__ noise, const __bf16* __restrict__ pWi,
    const float* __restrict__ b_init, float* __restrict__ h)
{
    __shared__ __align__(16) __bf16 sA[2 * 8192];
    __shared__ __align__(16) __bf16 sB[2 * 8192];
    const int m0 = blockIdx.y * 64, n0 = blockIdx.x * 64;
    f32x4 acc[2][2];
    gemm64_core(sA, sB, noise, 128, pWi, 2, m0, n0, 0, 128, acc);
    const int lane = threadIdx.x & 63, wid = threadIdx.x >> 6;
    const int wr = (wid >> 1) << 5, wc = (wid & 1) << 5;
    const int fr = lane & 15, kg = lane >> 4;
#pragma unroll
    for (int i = 0; i < 2; ++i)
#pragma unroll
        for (int j = 0; j < 2; ++j)
#pragma unroll
            for (int v = 0; v < 4; ++v) {
                const int row = m0 + wr + i * 16 + kg * 4 + v;
                const int col = n0 + wc + j * 16 + fr;
                h[(long long)row * 1024 + col] = acc[i][j][v] + b_init[col];
            }
}

// one-time h -> hp planes
__global__ __launch_bounds__(256) void k_cvt_hp(
    const float* __restrict__ h, __bf16* __restrict__ hp)
{
    const int flat = blockIdx.x * 256 + threadIdx.x;   // 32768
    const int b = flat >> 8, k4 = (flat & 255) << 2;
    const float4 v = *(const float4*)(h + (long long)b * 1024 + k4);
    const __bf16 h0 = (__bf16)v.x, h1 = (__bf16)v.y, h2 = (__bf16)v.z, h3 = (__bf16)v.w;
    const __bf16 l0 = (__bf16)(v.x - (float)h0);
    const __bf16 l1 = (__bf16)(v.y - (float)h1);
    const __bf16 l2 = (__bf16)(v.z - (float)h2);
    const __bf16 l3 = (__bf16)(v.w - (float)h3);
    const long long tb = ((long long)(b >> 6) * 16 + (k4 >> 6)) * 8192;
    const int e = swz_e(b, k4);
    *(bf16x4*)&hp[tb + e] = (bf16x4){h0, h1, h2, h3};
    *(bf16x4*)&hp[tb + 4096 + e] = (bf16x4){l0, l1, l2, l3};
}

// W[N][K] fp32 -> planes tile-major, swizzle baked
__global__ __launch_bounds__(256) void k_prep_wt(
    const float* __restrict__ W, __bf16* __restrict__ P, int K)
{
    const int idx = blockIdx.x * 256 + threadIdx.x;
    const int kq = K >> 2;
    const int n = idx / kq;
    const int k4 = (idx - n * kq) << 2;
    const float4 v = *(const float4*)(W + (long long)n * K + k4);
    const __bf16 h0 = (__bf16)v.x, h1 = (__bf16)v.y, h2 = (__bf16)v.z, h3 = (__bf16)v.w;
    const __bf16 l0 = (__bf16)(v.x - (float)h0);
    const __bf16 l1 = (__bf16)(v.y - (float)h1);
    const __bf16 l2 = (__bf16)(v.z - (float)h2);
    const __bf16 l3 = (__bf16)(v.w - (float)h3);
    const long long tbase = ((long long)(n >> 6) * (K >> 6) + (k4 >> 6)) * 8192;
    const int e = swz_e(n, k4);
    *(bf16x4*)&P[tbase + e] = (bf16x4){h0, h1, h2, h3};
    *(bf16x4*)&P[tbase + 4096 + e] = (bf16x4){l0, l1, l2, l3};
}

// Et planes: B[N=256(d)][K=8192(v)] from E[8192][256]
__global__ __launch_bounds__(256) void k_prep_et(
    const float* __restrict__ E, __bf16* __restrict__ P)
{
    const int idx = blockIdx.x * 256 + threadIdx.x;
    const int d = idx & 255;
    const int v4 = (idx >> 8) << 2;
    float xx[4];
#pragma unroll
    for (int j = 0; j < 4; ++j)
        xx[j] = E[(long long)(v4 + j) * 256 + d];
    __bf16 hh[4], ll[4];
#pragma unroll
    for (int j = 0; j < 4; ++j) {
        hh[j] = (__bf16)xx[j];
        ll[j] = (__bf16)(xx[j] - (float)hh[j]);
    }
    const long long tbase = ((long long)(d >> 6) * 128 + (v4 >> 6)) * 8192;
    const int e = swz_e(d, v4);
    *(bf16x4*)&P[tbase + e] = (bf16x4){hh[0], hh[1], hh[2], hh[3]};
    *(bf16x4*)&P[tbase + 4096 + e] = (bf16x4){ll[0], ll[1], ll[2], ll[3]};
}

__global__ void k_zero(float* __restrict__ x) {
    x[blockIdx.x * 256 + threadIdx.x] = 0.f;
}

// ---------------- gumbel + softmax ----------------
__device__ __forceinline__ float wred_max(float v) {
#pragma unroll
    for (int off = 32; off > 0; off >>= 1)
        v = fmaxf(v, __shfl_down(v, off, 64));
    return v;
}
__device__ __forceinline__ float wred_sum(float v) {
#pragma unroll
    for (int off = 32; off > 0; off >>= 1)
        v += __shfl_down(v, off, 64);
    return v;
}

__global__ __launch_bounds__(1024) void k_sample(
    const float* __restrict__ lg0, const float* __restrict__ lg1,
    const float* __restrict__ b_out, const float* __restrict__ temp,
    float* __restrict__ out, float* __restrict__ x, int t)
{
    const int b = blockIdx.x;
    const int tid = threadIdx.x;

    const int gid = b * 1024 + tid;
    if (gid < 128 * 256) x[gid] = 0.f;

    uint32_t k0t, k1t;
    threefry2x32(0u, 42u, 0u, (uint32_t)t, k0t, k1t);

    const float tau = temp[0];
    float s[8];
    float m = -3.4e38f;
#pragma unroll
    for (int j = 0; j < 8; ++j) {
        const int v = tid + j * 1024;
        const float lg = lg0[b * 8192 + v] + lg1[b * 8192 + v] + b_out[v];
        const uint32_t idx = (uint32_t)(b * 8192 + v);
        uint32_t o0, o1;
        threefry2x32(k0t, k1t, 0u, idx, o0, o1);
        const uint32_t bits = o0 ^ o1;
        float f = __uint_as_float((bits >> 9) | 0x3f800000u) - 1.0f;
        if (f == 0.0f) f = 1.17549435e-38f;
        const float g = -logf(-logf(f));
        s[j] = (lg + g) / tau;
        m = fmaxf(m, s[j]);
    }

    __shared__ float red[16];
    const int lane = tid & 63, wid = tid >> 6;

    float wm = wred_max(m);
    if (lane == 0) red[wid] = wm;
    __syncthreads();
    if (tid < 64) {
        float v = (tid < 16) ? red[tid] : -3.4e38f;
        v = wred_max(v);
        if (tid == 0) red[0] = v;
    }
    __syncthreads();
    m = red[0];
    __syncthreads();

    float e[8];
    float sum = 0.f;
#pragma unroll
    for (int j = 0; j < 8; ++j) {
        e[j] = expf(s[j] - m);
        sum += e[j];
    }
    float ws_ = wred_sum(sum);
    if (lane == 0) red[wid] = ws_;
    __syncthreads();
    if (tid < 64) {
        float v = (tid < 16) ? red[tid] : 0.f;
        v = wred_sum(v);
        if (tid == 0) red[0] = v;
    }
    __syncthreads();
    const float inv = 1.0f / red[0];

    const size_t obase = ((size_t)b * 128 + (size_t)t) * 8192;
#pragma unroll
    for (int j = 0; j < 8; ++j)
        out[obase + tid + j * 1024] = e[j] * inv;
}

// ---------------- launch ----------------
extern "C" void kernel_launch(void* const* d_in, const int* in_sizes, int n_in,
                              void* d_out, int out_size, void* d_ws, size_t ws_size,
                              hipStream_t stream) {
    (void)in_sizes; (void)n_in; (void)out_size; (void)ws_size;
    const float* noise  = (const float*)d_in[0];
    const float* temp   = (const float*)d_in[1];
    const float* W_init = (const float*)d_in[2];
    const float* b_init = (const float*)d_in[3];
    const float* E      = (const float*)d_in[4];
    const float* W_ih   = (const float*)d_in[5];
    const float* W_hh   = (const float*)d_in[6];
    const float* b_ih   = (const float*)d_in[7];
    const float* b_hh   = (const float*)d_in[8];
    const float* W_out  = (const float*)d_in[9];
    const float* b_out  = (const float*)d_in[10];
    float* out = (float*)d_out;

    float* ws  = (float*)d_ws;
    float* h   = ws;                    // 128*1024
    float* x   = h   + 131072;          // 128*256
    float* gh0 = x   + 32768;           // 128*3072
    float* gh1 = gh0 + 393216;          // 128*3072
    float* lg0 = gh1 + 393216;          // 128*8192
    float* lg1 = lg0 + 1048576;         // 128*8192
    __bf16* pWi = (__bf16*)(lg1 + 1048576);          // 1024*128  -> 131072 f-slots
    __bf16* pIH = (__bf16*)((float*)pWi + 131072);   // 3072*256  -> 786432
    __bf16* pHH = (__bf16*)((float*)pIH + 786432);   // 3072*1024 -> 3145728
    __bf16* pWo = (__bf16*)((float*)pHH + 3145728);  // 8192*1024 -> 8388608
    __bf16* pEt = (__bf16*)((float*)pWo + 8388608);  // 256*8192  -> 2097152
    __bf16* hp  = (__bf16*)((float*)pEt + 2097152);  // 128*1024  -> 131072

    // one-time: preconvert weights to swizzled bf16 hi/lo tile planes
    k_prep_wt<<<dim3(1024 * 128 / 4 / 256), dim3(256), 0, stream>>>(W_init, pWi, 128);
    k_prep_wt<<<dim3(3072 * 256 / 4 / 256), dim3(256), 0, stream>>>(W_ih, pIH, 256);
    k_prep_wt<<<dim3(3072 * 1024 / 4 / 256), dim3(256), 0, stream>>>(W_hh, pHH, 1024);
    k_prep_wt<<<dim3(8192 * 1024 / 4 / 256), dim3(256), 0, stream>>>(W_out, pWo, 1024);
    k_prep_et<<<dim3(8192 / 4 * 256 / 256), dim3(256), 0, stream>>>(E, pEt);

    k_zero<<<dim3(128), dim3(256), 0, stream>>>(x);
    k_h0<<<dim3(16, 2), dim3(256), 0, stream>>>(noise, pWi, b_init, h);
    k_cvt_hp<<<dim3(128), dim3(256), 0, stream>>>(h, hp);

    for (int t = 0; t < 128; ++t) {
        // K1: gh (plane, from hp) || embed (old core, atomic into x)
        k_embed_gh<<<dim3(224), dim3(256), 0, stream>>>(
            out, pEt, x, hp, pHH, gh0, gh1, t);
        // K2: gi + gates -> h, hp
        k_gigates<<<dim3(32), dim3(256), 0, stream>>>(
            x, pIH, b_ih, b_hh, gh0, gh1, h, hp);
        // K3: logits halves (plane, from hp)
        k_logits<<<dim3(128, 2), dim3(256), 0, stream>>>(hp, pWo, lg0, lg1);
        // K4: gumbel + softmax -> y_t, zero x
        k_sample<<<dim3(128), dim3(1024), 0, stream>>>(lg0, lg1, b_out, temp, out, x, t);
    }
}

// Round 4
// 6234.682 us; speedup vs baseline: 1.2318x; 1.2318x over previous
//
#include <hip/hip_runtime.h>
#include <stdint.h>

// ---------------- threefry2x32 (bit-exact vs JAX) ----------------
__device__ __forceinline__ uint32_t rotl32(uint32_t v, int r) {
    return (v << r) | (v >> (32 - r));
}

__device__ __forceinline__ void threefry2x32(uint32_t k0, uint32_t k1,
                                             uint32_t x0, uint32_t x1,
                                             uint32_t& o0, uint32_t& o1) {
    const uint32_t k2 = k0 ^ k1 ^ 0x1BD11BDAu;
    x0 += k0; x1 += k1;
#define TF_RND(r) { x0 += x1; x1 = rotl32(x1, r); x1 ^= x0; }
    TF_RND(13) TF_RND(15) TF_RND(26) TF_RND(6)
    x0 += k1; x1 += k2 + 1u;
    TF_RND(17) TF_RND(29) TF_RND(16) TF_RND(24)
    x0 += k2; x1 += k0 + 2u;
    TF_RND(13) TF_RND(15) TF_RND(26) TF_RND(6)
    x0 += k0; x1 += k1 + 3u;
    TF_RND(17) TF_RND(29) TF_RND(16) TF_RND(24)
    x0 += k1; x1 += k2 + 4u;
    TF_RND(13) TF_RND(15) TF_RND(26) TF_RND(6)
    x0 += k2; x1 += k0 + 5u;
#undef TF_RND
    o0 = x0; o1 = x1;
}

// ---------------- shared GEMM machinery ----------------
// Plane format for a matrix [R][K]: 64x64 tiles, tile-major [R/64][K/64],
// each tile = [hi: 4096 bf16][lo: 4096 bf16], element e swizzled:
//   e = ((r&63)*64 + (k&63)) ^ ((r&7)<<3)
// 3-product split: a*b ~= ah*bh + al*bh + ah*bl (rel err ~2^-18).

typedef __attribute__((ext_vector_type(8))) __bf16 bf16x8;
typedef __attribute__((ext_vector_type(4))) __bf16 bf16x4;
typedef __attribute__((ext_vector_type(4))) float f32x4;

__device__ __forceinline__ int swz_e(int r, int c) {
    return ((r & 63) * 64 + (c & 63)) ^ ((r & 7) << 3);
}

__device__ __forceinline__ void async16(const void* g, void* l) {
    __builtin_amdgcn_global_load_lds(
        (const __attribute__((address_space(1))) uint32_t*)g,
        (__attribute__((address_space(3))) uint32_t*)l,
        16, 0, 0);
}

// stage one 16KB plane tile (hi+lo) global -> LDS, async, linear
__device__ __forceinline__ void stageB(const __bf16* src, __bf16* dst, int tid) {
    const int wid = tid >> 6, lane = tid & 63;
    const char* g = (const char*)src + wid * 4096 + lane * 16;
    char* l = (char*)dst + wid * 4096 + lane * 16;
#pragma unroll
    for (int c = 0; c < 4; ++c)
        async16(g + c * 1024, l + c * 1024);
}

// ---------------- 64x64 core (A fp32, cvt in-kernel) ----------------
__device__ __forceinline__ void loadA(const float* A, long long lda,
                                      int m0, int k0, int tid, float4* ar) {
#pragma unroll
    for (int i = 0; i < 4; ++i) {
        const int flat = i * 256 + tid;
        const int row = flat >> 4, k4 = (flat & 15) << 2;
        ar[i] = *(const float4*)(A + (long long)(m0 + row) * lda + (k0 + k4));
    }
}

__device__ __forceinline__ void cvtWriteA(const float4* ar, __bf16* Hs, int tid) {
#pragma unroll
    for (int i = 0; i < 4; ++i) {
        const int flat = i * 256 + tid;
        const int row = flat >> 4, k4 = (flat & 15) << 2;
        const float4 v = ar[i];
        const __bf16 h0 = (__bf16)v.x, h1 = (__bf16)v.y, h2 = (__bf16)v.z, h3 = (__bf16)v.w;
        const __bf16 l0 = (__bf16)(v.x - (float)h0);
        const __bf16 l1 = (__bf16)(v.y - (float)h1);
        const __bf16 l2 = (__bf16)(v.z - (float)h2);
        const __bf16 l3 = (__bf16)(v.w - (float)h3);
        const int e = swz_e(row, k4);
        *(bf16x4*)&Hs[e] = (bf16x4){h0, h1, h2, h3};
        *(bf16x4*)&Hs[4096 + e] = (bf16x4){l0, l1, l2, l3};
    }
}

// computes 64x64 acc: C_tile = A[m0:,kbase:kbase+ksize] @ B[n0B:,:]^T
__device__ __forceinline__ void gemm64_core(
    __bf16* sA, __bf16* sB,
    const float* __restrict__ A, long long lda,
    const __bf16* __restrict__ Bp, int bKt,
    int m0, int n0B, int kbase, int ksize,
    f32x4 acc[2][2])
{
    const int tid  = threadIdx.x;
    const int lane = tid & 63;
    const int wid  = tid >> 6;
    const int wr   = (wid >> 1) << 5;
    const int wc   = (wid & 1) << 5;
    const int fr   = lane & 15;
    const int kg   = lane >> 4;
    const int nt   = ksize >> 6;
    const long long btile0 = (long long)(n0B >> 6) * bKt + (kbase >> 6);

    acc[0][0] = (f32x4){0,0,0,0}; acc[0][1] = (f32x4){0,0,0,0};
    acc[1][0] = (f32x4){0,0,0,0}; acc[1][1] = (f32x4){0,0,0,0};
    float4 ar[4];

    stageB(Bp + btile0 * 8192, sB, tid);
    loadA(A, lda, m0, kbase, tid, ar);
    cvtWriteA(ar, sA, tid);
    __syncthreads();

    for (int t = 0; t < nt; ++t) {
        const int cur = t & 1, nxt = cur ^ 1;
        __bf16* sAc = sA + cur * 8192;
        __bf16* sBc = sB + cur * 8192;
        if (t + 1 < nt) {
            stageB(Bp + (btile0 + t + 1) * 8192, sB + nxt * 8192, tid);
            loadA(A, lda, m0, kbase + ((t + 1) << 6), tid, ar);
        }
#pragma unroll
        for (int kc = 0; kc < 2; ++kc) {
            const int kb = kc * 32 + kg * 8;
            bf16x8 ah[2], al[2], bh[2], bl[2];
#pragma unroll
            for (int i = 0; i < 2; ++i) {
                const int r  = wr + i * 16 + fr;
                const int ea = swz_e(r, kb);
                ah[i] = *(const bf16x8*)&sAc[ea];
                al[i] = *(const bf16x8*)&sAc[4096 + ea];
                const int cc = wc + i * 16 + fr;
                const int eb = swz_e(cc, kb);
                bh[i] = *(const bf16x8*)&sBc[eb];
                bl[i] = *(const bf16x8*)&sBc[4096 + eb];
            }
#pragma unroll
            for (int i = 0; i < 2; ++i)
#pragma unroll
                for (int j = 0; j < 2; ++j)
                    acc[i][j] = __builtin_amdgcn_mfma_f32_16x16x32_bf16(ah[i], bh[j], acc[i][j], 0, 0, 0);
#pragma unroll
            for (int i = 0; i < 2; ++i)
#pragma unroll
                for (int j = 0; j < 2; ++j)
                    acc[i][j] = __builtin_amdgcn_mfma_f32_16x16x32_bf16(al[i], bh[j], acc[i][j], 0, 0, 0);
#pragma unroll
            for (int i = 0; i < 2; ++i)
#pragma unroll
                for (int j = 0; j < 2; ++j)
                    acc[i][j] = __builtin_amdgcn_mfma_f32_16x16x32_bf16(ah[i], bl[j], acc[i][j], 0, 0, 0);
        }
        if (t + 1 < nt)
            cvtWriteA(ar, sA + nxt * 8192, tid);
        __syncthreads();
    }
}

// ---------------- plane GEMM: TM=128 (full M), TN=64 ----------------
// A from planes (per-lane global->reg), B from planes via global_load_lds.
__device__ __forceinline__ void plane_gemm(
    __bf16* sB,                                  // [2][8192]
    const __bf16* __restrict__ Ap, int aKt,
    const __bf16* __restrict__ Bp, int bKt,
    float* __restrict__ C, int ldc,
    int n0, int kbase, int ksize)
{
    const int tid  = threadIdx.x;
    const int lane = tid & 63;
    const int wid  = tid >> 6;
    const int wr   = wid << 5;
    const int fr   = lane & 15;
    const int kg   = lane >> 4;
    const int nt   = ksize >> 6;
    const int kt0  = kbase >> 6;
    const long long btile0 = (long long)(n0 >> 6) * bKt + kt0;

    f32x4 acc[2][4] = {};

    stageB(Bp + btile0 * 8192, sB, tid);
    __syncthreads();

    for (int t = 0; t < nt; ++t) {
        const int cur = t & 1;
        __bf16* sBc = sB + cur * 8192;
        if (t + 1 < nt)
            stageB(Bp + (btile0 + t + 1) * 8192, sB + (cur ^ 1) * 8192, tid);

        bf16x8 ah[2][2], al[2][2];               // [kc][i]
        const long long kt = (long long)(kt0 + t);
#pragma unroll
        for (int kc = 0; kc < 2; ++kc)
#pragma unroll
            for (int i = 0; i < 2; ++i) {
                const int r  = wr + i * 16 + fr;
                const int kb = kc * 32 + kg * 8;
                const long long ab = ((long long)(r >> 6) * aKt + kt) * 8192;
                const int ea = swz_e(r, kb);
                ah[kc][i] = *(const bf16x8*)&Ap[ab + ea];
                al[kc][i] = *(const bf16x8*)&Ap[ab + 4096 + ea];
            }
#pragma unroll
        for (int kc = 0; kc < 2; ++kc) {
            const int kb = kc * 32 + kg * 8;
            bf16x8 bh[4], bl[4];
#pragma unroll
            for (int j = 0; j < 4; ++j) {
                const int cc = j * 16 + fr;
                const int eb = swz_e(cc, kb);
                bh[j] = *(const bf16x8*)&sBc[eb];
                bl[j] = *(const bf16x8*)&sBc[4096 + eb];
            }
#pragma unroll
            for (int i = 0; i < 2; ++i)
#pragma unroll
                for (int j = 0; j < 4; ++j)
                    acc[i][j] = __builtin_amdgcn_mfma_f32_16x16x32_bf16(ah[kc][i], bh[j], acc[i][j], 0, 0, 0);
#pragma unroll
            for (int i = 0; i < 2; ++i)
#pragma unroll
                for (int j = 0; j < 4; ++j)
                    acc[i][j] = __builtin_amdgcn_mfma_f32_16x16x32_bf16(al[kc][i], bh[j], acc[i][j], 0, 0, 0);
#pragma unroll
            for (int i = 0; i < 2; ++i)
#pragma unroll
                for (int j = 0; j < 4; ++j)
                    acc[i][j] = __builtin_amdgcn_mfma_f32_16x16x32_bf16(ah[kc][i], bl[j], acc[i][j], 0, 0, 0);
        }
        __syncthreads();
    }

    // C/D layout: col = lane&15, row = (lane>>4)*4 + reg
#pragma unroll
    for (int i = 0; i < 2; ++i)
#pragma unroll
        for (int j = 0; j < 4; ++j)
#pragma unroll
            for (int v = 0; v < 4; ++v) {
                const int row = wr + i * 16 + kg * 4 + v;
                const int col = n0 + j * 16 + fr;
                C[(long long)row * ldc + col] = acc[i][j][v];
            }
}

// ---------------- per-step kernels ----------------

// L1: blocks 0..95: gh (plane, split-K=2); blocks 96..223: embed (atomic into x)
__global__ __launch_bounds__(256) void k_embed_gh(
    const float* __restrict__ out, const __bf16* __restrict__ pEt,
    float* __restrict__ x,
    const __bf16* __restrict__ hp, const __bf16* __restrict__ pHH,
    float* __restrict__ gh0, float* __restrict__ gh1, int t)
{
    __shared__ __align__(16) char smem[65536];
    const int bid = blockIdx.x;
    if (bid < 96) {
        __bf16* sB = (__bf16*)smem;
        const int n = bid >> 1, z = bid & 1;
        plane_gemm(sB, hp, 16, pHH, 16, z ? gh1 : gh0, 3072, n * 64, z * 512, 512);
    } else {
        if (t == 0) return;
        const int r = bid - 96;
        const int m0 = ((r >> 2) & 1) * 64;
        const int n0 = (r & 3) * 64;
        const int kbase = (r >> 3) * 512;
        const float* Y = out + (size_t)(t - 1) * 8192;
        __bf16* sA = (__bf16*)smem;
        __bf16* sB = (__bf16*)(smem + 32768);
        f32x4 acc[2][2];
        gemm64_core(sA, sB, Y, 128LL * 8192LL, pEt, 128, m0, n0, kbase, 512, acc);
        const int lane = threadIdx.x & 63, wid = threadIdx.x >> 6;
        const int wr = (wid >> 1) << 5, wc = (wid & 1) << 5;
        const int fr = lane & 15, kg = lane >> 4;
#pragma unroll
        for (int i = 0; i < 2; ++i)
#pragma unroll
            for (int j = 0; j < 2; ++j)
#pragma unroll
                for (int v = 0; v < 4; ++v) {
                    const int row = m0 + wr + i * 16 + kg * 4 + v;
                    const int col = n0 + wc + j * 16 + fr;
                    atomicAdd(&x[(long long)row * 256 + col], acc[i][j][v]);
                }
    }
}

// L2: gi = x @ W_ih^T (no bias; added in gates).  grid (48, 2) = 96 blocks.
__global__ __launch_bounds__(256) void k_gi(
    const float* __restrict__ x, const __bf16* __restrict__ pIH,
    float* __restrict__ gi)
{
    __shared__ __align__(16) __bf16 sA[2 * 8192];
    __shared__ __align__(16) __bf16 sB[2 * 8192];
    const int n0 = blockIdx.x * 64, m0 = blockIdx.y * 64;
    f32x4 acc[2][2];
    gemm64_core(sA, sB, x, 256, pIH, 4, m0, n0, 0, 256, acc);
    const int lane = threadIdx.x & 63, wid = threadIdx.x >> 6;
    const int wr = (wid >> 1) << 5, wc = (wid & 1) << 5;
    const int fr = lane & 15, kg = lane >> 4;
#pragma unroll
    for (int i = 0; i < 2; ++i)
#pragma unroll
        for (int j = 0; j < 2; ++j)
#pragma unroll
            for (int v = 0; v < 4; ++v) {
                const int row = m0 + wr + i * 16 + kg * 4 + v;
                const int col = n0 + wc + j * 16 + fr;
                gi[(long long)row * 3072 + col] = acc[i][j][v];
            }
}

// L3: gates (elementwise, float4). h = (1-z)*n + z*h; emits h and hp planes.
__global__ __launch_bounds__(256) void k_gates(
    const float* __restrict__ gi,
    const float* __restrict__ gh0, const float* __restrict__ gh1,
    const float* __restrict__ b_ih, const float* __restrict__ b_hh,
    float* __restrict__ h, __bf16* __restrict__ hp)
{
    const int t4 = blockIdx.x * 256 + threadIdx.x;   // 32768 = 128*1024/4
    const int b = t4 >> 8;
    const int c4 = (t4 & 255) << 2;
    const long long g = (long long)b * 3072 + c4;

    const float4 giR = *(const float4*)(gi + g);
    const float4 giZ = *(const float4*)(gi + g + 1024);
    const float4 giN = *(const float4*)(gi + g + 2048);
    const float4 h0R = *(const float4*)(gh0 + g);
    const float4 h0Z = *(const float4*)(gh0 + g + 1024);
    const float4 h0N = *(const float4*)(gh0 + g + 2048);
    const float4 h1R = *(const float4*)(gh1 + g);
    const float4 h1Z = *(const float4*)(gh1 + g + 1024);
    const float4 h1N = *(const float4*)(gh1 + g + 2048);
    const float4 biR = *(const float4*)(b_ih + c4);
    const float4 biZ = *(const float4*)(b_ih + c4 + 1024);
    const float4 biN = *(const float4*)(b_ih + c4 + 2048);
    const float4 bhR = *(const float4*)(b_hh + c4);
    const float4 bhZ = *(const float4*)(b_hh + c4 + 1024);
    const float4 bhN = *(const float4*)(b_hh + c4 + 2048);
    float4 hv = *(const float4*)(h + (long long)b * 1024 + c4);

    float ho[4];
    const float gr[4] = {giR.x + biR.x + h0R.x + h1R.x + bhR.x,
                         giR.y + biR.y + h0R.y + h1R.y + bhR.y,
                         giR.z + biR.z + h0R.z + h1R.z + bhR.z,
                         giR.w + biR.w + h0R.w + h1R.w + bhR.w};
    const float gz[4] = {giZ.x + biZ.x + h0Z.x + h1Z.x + bhZ.x,
                         giZ.y + biZ.y + h0Z.y + h1Z.y + bhZ.y,
                         giZ.z + biZ.z + h0Z.z + h1Z.z + bhZ.z,
                         giZ.w + biZ.w + h0Z.w + h1Z.w + bhZ.w};
    const float gnI[4] = {giN.x + biN.x, giN.y + biN.y, giN.z + biN.z, giN.w + biN.w};
    const float gnH[4] = {h0N.x + h1N.x + bhN.x, h0N.y + h1N.y + bhN.y,
                          h0N.z + h1N.z + bhN.z, h0N.w + h1N.w + bhN.w};
    const float hin[4] = {hv.x, hv.y, hv.z, hv.w};
#pragma unroll
    for (int q = 0; q < 4; ++q) {
        const float r = 1.f / (1.f + expf(-gr[q]));
        const float z = 1.f / (1.f + expf(-gz[q]));
        const float n = tanhf(gnI[q] + r * gnH[q]);
        ho[q] = (1.f - z) * n + z * hin[q];
    }
    *(float4*)(h + (long long)b * 1024 + c4) = (float4){ho[0], ho[1], ho[2], ho[3]};

    __bf16 hh[4], hl[4];
#pragma unroll
    for (int q = 0; q < 4; ++q) {
        hh[q] = (__bf16)ho[q];
        hl[q] = (__bf16)(ho[q] - (float)hh[q]);
    }
    const long long tb = ((long long)(b >> 6) * 16 + (c4 >> 6)) * 8192;
    const int e = swz_e(b, c4);
    *(bf16x4*)&hp[tb + e] = (bf16x4){hh[0], hh[1], hh[2], hh[3]};
    *(bf16x4*)&hp[tb + 4096 + e] = (bf16x4){hl[0], hl[1], hl[2], hl[3]};
}

// L4: logits split-K=4 via plane GEMM.  grid (128, 4) = 512 blocks.
__global__ __launch_bounds__(256) void k_logits(
    const __bf16* __restrict__ hp, const __bf16* __restrict__ pWo,
    float* __restrict__ lg)
{
    __shared__ __align__(16) __bf16 sB[2 * 8192];
    const int n = blockIdx.x, z = blockIdx.y;
    plane_gemm(sB, hp, 16, pWo, 16, lg + (size_t)z * 1048576, 8192,
               n * 64, z * 256, 256);
}

// ---------------- one-time kernels ----------------
__global__ __launch_bounds__(256) void k_h0(
    const float* __restrict__ noise, const __bf16* __restrict__ pWi,
    const float* __restrict__ b_init, float* __restrict__ h)
{
    __shared__ __align__(16) __bf16 sA[2 * 8192];
    __shared__ __align__(16) __bf16 sB[2 * 8192];
    const int m0 = blockIdx.y * 64, n0 = blockIdx.x * 64;
    f32x4 acc[2][2];
    gemm64_core(sA, sB, noise, 128, pWi, 2, m0, n0, 0, 128, acc);
    const int lane = threadIdx.x & 63, wid = threadIdx.x >> 6;
    const int wr = (wid >> 1) << 5, wc = (wid & 1) << 5;
    const int fr = lane & 15, kg = lane >> 4;
#pragma unroll
    for (int i = 0; i < 2; ++i)
#pragma unroll
        for (int j = 0; j < 2; ++j)
#pragma unroll
            for (int v = 0; v < 4; ++v) {
                const int row = m0 + wr + i * 16 + kg * 4 + v;
                const int col = n0 + wc + j * 16 + fr;
                h[(long long)row * 1024 + col] = acc[i][j][v] + b_init[col];
            }
}

// one-time h -> hp planes
__global__ __launch_bounds__(256) void k_cvt_hp(
    const float* __restrict__ h, __bf16* __restrict__ hp)
{
    const int flat = blockIdx.x * 256 + threadIdx.x;   // 32768
    const int b = flat >> 8, k4 = (flat & 255) << 2;
    const float4 v = *(const float4*)(h + (long long)b * 1024 + k4);
    const __bf16 h0 = (__bf16)v.x, h1 = (__bf16)v.y, h2 = (__bf16)v.z, h3 = (__bf16)v.w;
    const __bf16 l0 = (__bf16)(v.x - (float)h0);
    const __bf16 l1 = (__bf16)(v.y - (float)h1);
    const __bf16 l2 = (__bf16)(v.z - (float)h2);
    const __bf16 l3 = (__bf16)(v.w - (float)h3);
    const long long tb = ((long long)(b >> 6) * 16 + (k4 >> 6)) * 8192;
    const int e = swz_e(b, k4);
    *(bf16x4*)&hp[tb + e] = (bf16x4){h0, h1, h2, h3};
    *(bf16x4*)&hp[tb + 4096 + e] = (bf16x4){l0, l1, l2, l3};
}

// W[N][K] fp32 -> planes tile-major, swizzle baked
__global__ __launch_bounds__(256) void k_prep_wt(
    const float* __restrict__ W, __bf16* __restrict__ P, int K)
{
    const int idx = blockIdx.x * 256 + threadIdx.x;
    const int kq = K >> 2;
    const int n = idx / kq;
    const int k4 = (idx - n * kq) << 2;
    const float4 v = *(const float4*)(W + (long long)n * K + k4);
    const __bf16 h0 = (__bf16)v.x, h1 = (__bf16)v.y, h2 = (__bf16)v.z, h3 = (__bf16)v.w;
    const __bf16 l0 = (__bf16)(v.x - (float)h0);
    const __bf16 l1 = (__bf16)(v.y - (float)h1);
    const __bf16 l2 = (__bf16)(v.z - (float)h2);
    const __bf16 l3 = (__bf16)(v.w - (float)h3);
    const long long tbase = ((long long)(n >> 6) * (K >> 6) + (k4 >> 6)) * 8192;
    const int e = swz_e(n, k4);
    *(bf16x4*)&P[tbase + e] = (bf16x4){h0, h1, h2, h3};
    *(bf16x4*)&P[tbase + 4096 + e] = (bf16x4){l0, l1, l2, l3};
}

// Et planes: B[N=256(d)][K=8192(v)] from E[8192][256]
__global__ __launch_bounds__(256) void k_prep_et(
    const float* __restrict__ E, __bf16* __restrict__ P)
{
    const int idx = blockIdx.x * 256 + threadIdx.x;
    const int d = idx & 255;
    const int v4 = (idx >> 8) << 2;
    float xx[4];
#pragma unroll
    for (int j = 0; j < 4; ++j)
        xx[j] = E[(long long)(v4 + j) * 256 + d];
    __bf16 hh[4], ll[4];
#pragma unroll
    for (int j = 0; j < 4; ++j) {
        hh[j] = (__bf16)xx[j];
        ll[j] = (__bf16)(xx[j] - (float)hh[j]);
    }
    const long long tbase = ((long long)(d >> 6) * 128 + (v4 >> 6)) * 8192;
    const int e = swz_e(d, v4);
    *(bf16x4*)&P[tbase + e] = (bf16x4){hh[0], hh[1], hh[2], hh[3]};
    *(bf16x4*)&P[tbase + 4096 + e] = (bf16x4){ll[0], ll[1], ll[2], ll[3]};
}

__global__ void k_zero(float* __restrict__ x) {
    x[blockIdx.x * 256 + threadIdx.x] = 0.f;
}

// ---------------- gumbel + softmax ----------------
__device__ __forceinline__ float wred_max(float v) {
#pragma unroll
    for (int off = 32; off > 0; off >>= 1)
        v = fmaxf(v, __shfl_down(v, off, 64));
    return v;
}
__device__ __forceinline__ float wred_sum(float v) {
#pragma unroll
    for (int off = 32; off > 0; off >>= 1)
        v += __shfl_down(v, off, 64);
    return v;
}

__global__ __launch_bounds__(1024) void k_sample(
    const float* __restrict__ lg, const float* __restrict__ b_out,
    const float* __restrict__ temp,
    float* __restrict__ out, float* __restrict__ x, int t)
{
    const int b = blockIdx.x;
    const int tid = threadIdx.x;

    const int gid = b * 1024 + tid;
    if (gid < 128 * 256) x[gid] = 0.f;

    uint32_t k0t, k1t;
    threefry2x32(0u, 42u, 0u, (uint32_t)t, k0t, k1t);

    const float tau = temp[0];
    float s[8];
    float m = -3.4e38f;
#pragma unroll
    for (int j = 0; j < 8; ++j) {
        const int v = tid + j * 1024;
        const size_t o = (size_t)b * 8192 + v;
        const float lgv = lg[o] + lg[o + 1048576] + lg[o + 2097152] + lg[o + 3145728]
                        + b_out[v];
        const uint32_t idx = (uint32_t)(b * 8192 + v);
        uint32_t o0, o1;
        threefry2x32(k0t, k1t, 0u, idx, o0, o1);
        const uint32_t bits = o0 ^ o1;
        float f = __uint_as_float((bits >> 9) | 0x3f800000u) - 1.0f;
        if (f == 0.0f) f = 1.17549435e-38f;
        const float g = -logf(-logf(f));
        s[j] = (lgv + g) / tau;
        m = fmaxf(m, s[j]);
    }

    __shared__ float red[16];
    const int lane = tid & 63, wid = tid >> 6;

    float wm = wred_max(m);
    if (lane == 0) red[wid] = wm;
    __syncthreads();
    if (tid < 64) {
        float v = (tid < 16) ? red[tid] : -3.4e38f;
        v = wred_max(v);
        if (tid == 0) red[0] = v;
    }
    __syncthreads();
    m = red[0];
    __syncthreads();

    float e[8];
    float sum = 0.f;
#pragma unroll
    for (int j = 0; j < 8; ++j) {
        e[j] = expf(s[j] - m);
        sum += e[j];
    }
    float ws_ = wred_sum(sum);
    if (lane == 0) red[wid] = ws_;
    __syncthreads();
    if (tid < 64) {
        float v = (tid < 16) ? red[tid] : 0.f;
        v = wred_sum(v);
        if (tid == 0) red[0] = v;
    }
    __syncthreads();
    const float inv = 1.0f / red[0];

    const size_t obase = ((size_t)b * 128 + (size_t)t) * 8192;
#pragma unroll
    for (int j = 0; j < 8; ++j)
        out[obase + tid + j * 1024] = e[j] * inv;
}

// ---------------- launch ----------------
extern "C" void kernel_launch(void* const* d_in, const int* in_sizes, int n_in,
                              void* d_out, int out_size, void* d_ws, size_t ws_size,
                              hipStream_t stream) {
    (void)in_sizes; (void)n_in; (void)out_size; (void)ws_size;
    const float* noise  = (const float*)d_in[0];
    const float* temp   = (const float*)d_in[1];
    const float* W_init = (const float*)d_in[2];
    const float* b_init = (const float*)d_in[3];
    const float* E      = (const float*)d_in[4];
    const float* W_ih   = (const float*)d_in[5];
    const float* W_hh   = (const float*)d_in[6];
    const float* b_ih   = (const float*)d_in[7];
    const float* b_hh   = (const float*)d_in[8];
    const float* W_out  = (const float*)d_in[9];
    const float* b_out  = (const float*)d_in[10];
    float* out = (float*)d_out;

    float* ws  = (float*)d_ws;
    float* h   = ws;                    // 128*1024
    float* x   = h   + 131072;          // 128*256
    float* gi  = x   + 32768;           // 128*3072
    float* gh0 = gi  + 393216;          // 128*3072
    float* gh1 = gh0 + 393216;          // 128*3072
    float* lg  = gh1 + 393216;          // 4 * 128*8192 = 4194304
    __bf16* pWi = (__bf16*)(lg + 4194304);           // 1024*128  -> 131072 f-slots
    __bf16* pIH = (__bf16*)((float*)pWi + 131072);   // 3072*256  -> 786432
    __bf16* pHH = (__bf16*)((float*)pIH + 786432);   // 3072*1024 -> 3145728
    __bf16* pWo = (__bf16*)((float*)pHH + 3145728);  // 8192*1024 -> 8388608
    __bf16* pEt = (__bf16*)((float*)pWo + 8388608);  // 256*8192  -> 2097152
    __bf16* hp  = (__bf16*)((float*)pEt + 2097152);  // 128*1024  -> 131072

    // one-time: preconvert weights to swizzled bf16 hi/lo tile planes
    k_prep_wt<<<dim3(1024 * 128 / 4 / 256), dim3(256), 0, stream>>>(W_init, pWi, 128);
    k_prep_wt<<<dim3(3072 * 256 / 4 / 256), dim3(256), 0, stream>>>(W_ih, pIH, 256);
    k_prep_wt<<<dim3(3072 * 1024 / 4 / 256), dim3(256), 0, stream>>>(W_hh, pHH, 1024);
    k_prep_wt<<<dim3(8192 * 1024 / 4 / 256), dim3(256), 0, stream>>>(W_out, pWo, 1024);
    k_prep_et<<<dim3(8192 / 4 * 256 / 256), dim3(256), 0, stream>>>(E, pEt);

    k_zero<<<dim3(128), dim3(256), 0, stream>>>(x);
    k_h0<<<dim3(16, 2), dim3(256), 0, stream>>>(noise, pWi, b_init, h);
    k_cvt_hp<<<dim3(128), dim3(256), 0, stream>>>(h, hp);

    for (int t = 0; t < 128; ++t) {
        // L1: gh (plane, from hp) || embed (atomic into x)
        k_embed_gh<<<dim3(224), dim3(256), 0, stream>>>(
            out, pEt, x, hp, pHH, gh0, gh1, t);
        // L2: gi = x @ W_ih^T
        k_gi<<<dim3(48, 2), dim3(256), 0, stream>>>(x, pIH, gi);
        // L3: gates -> h, hp
        k_gates<<<dim3(128), dim3(256), 0, stream>>>(
            gi, gh0, gh1, b_ih, b_hh, h, hp);
        // L4: logits split-K=4 (plane, from hp)
        k_logits<<<dim3(128, 4), dim3(256), 0, stream>>>(hp, pWo, lg);
        // L5: gumbel + softmax -> y_t, zero x
        k_sample<<<dim3(128), dim3(1024), 0, stream>>>(lg, b_out, temp, out, x, t);
    }
}